// Round 8
// baseline (49.060 us; speedup 1.0000x reference)
//
#include <hip/hip_runtime.h>

// PairwiseRankLoss: U=262144 users x G=64 items, K=2, MARGIN=0.3
// 4 users per 64-lane wave (16 lanes/user, 4 items/lane, float4 loads),
// two 4-user groups per loop body (loads force-materialized up front).
// R8: SIGNED-SPACE bitonic sort — values carry the block-direction sign
// (v_xor with loop-invariant per-lane constants at stage-group entry), so
//   - in-lane CEs are direction-free fmin/fmax (2 ops/pair, no cndmask)
//   - cross-lane CEs = v_mov_b32_dpp + fmin + fmax + ONE v_cndmask with a
//     loop-invariant SGPR-pair lane mask (inline asm)
// Median: sort both 32-halves ascending, split vs xor-15 mirrored half,
// a31 = max(lower 32); pos = yt > a31 (== yt > median, ties included).
// Top-2 rand/side: in-lane (m1,m2) + ror-fold on exact u32 r-bits; locate
// via ballot (lowest flat index on ties = lax.top_k); gather via __shfl.
// Deterministic two-stage reduction via d_ws.

static constexpr int kUsers = 262144;
static constexpr int kBlock = 256;                  // 4 waves / block
static constexpr int kGrid  = 2048;
static constexpr int kWavesPerBlock = kBlock / 64;
static constexpr int kTotalWaves = kGrid * kWavesPerBlock;   // 8192
static constexpr int kUsersPerWave = kUsers / kTotalWaves;   // 32
static constexpr int kUsersPerBody = 8;                      // 2 groups x 4
static constexpr int kBodies = kUsersPerWave / kUsersPerBody; // 4
static constexpr float kMargin = 0.3f;

template<int CTRL>
static __device__ __forceinline__ float movdppf(float x) {
    return __uint_as_float((unsigned)__builtin_amdgcn_mov_dpp(
        (int)__float_as_uint(x), CTRL, 0xF, 0xF, false));
}
template<int CTRL>
static __device__ __forceinline__ unsigned movdppu(unsigned x) {
    return (unsigned)__builtin_amdgcn_mov_dpp((int)x, CTRL, 0xF, 0xF, false);
}
template<int PAT>
static __device__ __forceinline__ float swzf(float x) {
    return __uint_as_float((unsigned)__builtin_amdgcn_ds_swizzle(
        (int)__float_as_uint(x), PAT));
}
static __device__ __forceinline__ float xorf(float x, unsigned m) {
    return __uint_as_float(__float_as_uint(x) ^ m);
}
// D = keep[lane] ? mn : mx  (single v_cndmask with SGPR-pair mask)
static __device__ __forceinline__ float cnd(float mx, float mn,
                                            unsigned long long keep) {
    float d;
    asm("v_cndmask_b32 %0, %1, %2, %3" : "=v"(d) : "v"(mx), "v"(mn), "s"(keep));
    return d;
}
// cross-lane compare-exchange in signed space: keep-min lanes per mask
template<int CTRL>
static __device__ __forceinline__ float cexd(float w, unsigned long long keep) {
    const float p = movdppf<CTRL>(w);
    return cnd(fmaxf(w, p), fminf(w, p), keep);
}
static __device__ __forceinline__ float cexswz(float w, unsigned long long keep) {
    const float p = swzf<0x101F>(w);           // xor-4 over lanes
    return cnd(fmaxf(w, p), fminf(w, p), keep);
}
static __device__ __forceinline__ unsigned umax_(unsigned a, unsigned b){ return a>b?a:b; }
static __device__ __forceinline__ unsigned umin_(unsigned a, unsigned b){ return a<b?a:b; }

#define CE2A(a, b) { float mn_=fminf(a,b), mx_=fmaxf(a,b); (a)=mn_; (b)=mx_; }
#define CE2D(a, b) { float mn_=fminf(a,b), mx_=fmaxf(a,b); (a)=mx_; (b)=mn_; }
#define FLIP4(m)   { w0=xorf(w0,m); w1=xorf(w1,m); w2=xorf(w2,m); w3=xorf(w3,m); }
#define FOLD2(m1, m2, CTRL) { \
    unsigned q1_ = movdppu<CTRL>(m1), q2_ = movdppu<CTRL>(m2); \
    unsigned lo_ = umin_(m1, q1_); \
    m1 = umax_(m1, q1_); \
    m2 = umax_(lo_, umax_(m2, q2_)); }

__global__ __launch_bounds__(kBlock, 6)
void prl_user_kernel(const float* __restrict__ y_hat,
                     const float* __restrict__ y_true,
                     const float* __restrict__ rnd,
                     float* __restrict__ partials)
{
    const int lane = threadIdx.x & 63;
    const int wid  = (blockIdx.x * kBlock + threadIdx.x) >> 6;
    const int t    = lane & 15;          // lane within user group
    const int g    = lane >> 4;          // user group (0..3) within wave
    const int tt   = t & 7;              // lane within 32-item sort half

    // loop-invariant sign-flip constants (VGPR) and keep-min masks (SGPR pair)
    const unsigned SGN   = 0x80000000u;
    const unsigned flipA = (tt & 1) ? SGN : 0u;                    // enter k=4
    const unsigned flipB = (((tt) ^ (tt >> 1)) & 1) ? SGN : 0u;    // k=4 -> k=8
    const unsigned flipC = (((tt >> 1) ^ (tt >> 2)) & 1) ? SGN : 0u; // 8 -> 16
    const unsigned flipD = ((tt >> 2) & 1) ? SGN : 0u;             // 16 -> 32
    const unsigned long long keep1 = __ballot((tt & 1) == 0);
    const unsigned long long keep2 = __ballot((tt & 2) == 0);
    const unsigned long long keep4 = __ballot((tt & 4) == 0);

    auto process = [&](float4 vh, float4 vt, float4 vr) -> float {
        // ---- signed-space bitonic: sort both 32-halves ascending ----
        float w0 = vt.x, w1 = vt.y, w2 = vt.z, w3 = vt.w;
        // k=2 (true space, compile-time dirs)
        CE2A(w0, w1); CE2D(w2, w3);
        // k=4
        FLIP4(flipA);
        CE2A(w0, w2); CE2A(w1, w3);      // j=2
        CE2A(w0, w1); CE2A(w2, w3);      // j=1
        // k=8
        FLIP4(flipB);
        w0 = cexd<0xB1>(w0, keep1); w1 = cexd<0xB1>(w1, keep1);  // j=4
        w2 = cexd<0xB1>(w2, keep1); w3 = cexd<0xB1>(w3, keep1);
        CE2A(w0, w2); CE2A(w1, w3);
        CE2A(w0, w1); CE2A(w2, w3);
        // k=16
        FLIP4(flipC);
        w0 = cexd<0x4E>(w0, keep2); w1 = cexd<0x4E>(w1, keep2);  // j=8
        w2 = cexd<0x4E>(w2, keep2); w3 = cexd<0x4E>(w3, keep2);
        w0 = cexd<0xB1>(w0, keep1); w1 = cexd<0xB1>(w1, keep1);  // j=4
        w2 = cexd<0xB1>(w2, keep1); w3 = cexd<0xB1>(w3, keep1);
        CE2A(w0, w2); CE2A(w1, w3);
        CE2A(w0, w1); CE2A(w2, w3);
        // k=32 (both halves ascending; back to true space)
        FLIP4(flipD);
        w0 = cexswz(w0, keep4); w1 = cexswz(w1, keep4);          // j=16
        w2 = cexswz(w2, keep4); w3 = cexswz(w3, keep4);
        w0 = cexd<0x4E>(w0, keep2); w1 = cexd<0x4E>(w1, keep2);  // j=8
        w2 = cexd<0x4E>(w2, keep2); w3 = cexd<0x4E>(w3, keep2);
        w0 = cexd<0xB1>(w0, keep1); w1 = cexd<0xB1>(w1, keep1);  // j=4
        w2 = cexd<0xB1>(w2, keep1); w3 = cexd<0xB1>(w3, keep1);
        CE2A(w0, w2); CE2A(w1, w3);
        CE2A(w0, w1); CE2A(w2, w3);

        // ---- split vs xor-15 mirrored other half: lower-32 multiset ----
        const float l0 = fminf(w0, swzf<0x3C1F>(w3));
        const float l1 = fminf(w1, swzf<0x3C1F>(w2));
        const float l2 = fminf(w2, swzf<0x3C1F>(w1));
        const float l3 = fminf(w3, swzf<0x3C1F>(w0));

        // a31 = max of lower 32 (uniform within 16-row after ror folds)
        float m = fmaxf(fmaxf(l0, l1), fmaxf(l2, l3));
        m = fmaxf(m, movdppf<0x128>(m));
        m = fmaxf(m, movdppf<0x124>(m));
        m = fmaxf(m, movdppf<0x122>(m));
        m = fmaxf(m, movdppf<0x121>(m));
        const float a31 = m;

        const bool p0m = vt.x > a31, p1m = vt.y > a31,
                   p2m = vt.z > a31, p3m = vt.w > a31;
        const unsigned rb0 = __float_as_uint(vr.x), rb1 = __float_as_uint(vr.y),
                       rb2 = __float_as_uint(vr.z), rb3 = __float_as_uint(vr.w);

        float P0, P1, N0, N1;
        #pragma unroll
        for (int side = 0; side < 2; ++side) {
            const unsigned k0 = ((side == 0) ? p0m : !p0m) ? rb0 : 0u;
            const unsigned k1 = ((side == 0) ? p1m : !p1m) ? rb1 : 0u;
            const unsigned k2 = ((side == 0) ? p2m : !p2m) ? rb2 : 0u;
            const unsigned k3 = ((side == 0) ? p3m : !p3m) ? rb3 : 0u;
            // in-lane top-2 of 4
            const unsigned a1 = umax_(k0,k1), a2 = umin_(k0,k1);
            const unsigned b1 = umax_(k2,k3), b2 = umin_(k2,k3);
            unsigned m1 = umax_(a1,b1);
            unsigned m2 = umax_(umin_(a1,b1), umax_(a2,b2));
            // ror-fold (m1,m2) across 16 lanes; group-uniform result
            FOLD2(m1, m2, 0x128);
            FOLD2(m1, m2, 0x124);
            FOLD2(m1, m2, 0x122);
            FOLD2(m1, m2, 0x121);

            float A[2];
            const unsigned vv[2] = { m1, m2 };
            #pragma unroll
            for (int j = 0; j < 2; ++j) {
                const unsigned V = vv[j];
                const bool c0 = (k0 == V), c1 = (k1 == V),
                           c2 = (k2 == V), c3 = (k3 == V);
                const float val = c0 ? vh.x : (c1 ? vh.y : (c2 ? vh.z : vh.w));
                const unsigned long long bal = __ballot(c0 | c1 | c2 | c3);
                const unsigned fld = (unsigned)(bal >> (g << 4)) & 0xFFFFu;
                const int tw = __builtin_ctz(fld);
                A[j] = __shfl(val, (lane & 48) | tw);
            }
            if (side == 0) { P0 = A[0]; P1 = A[1]; }
            else           { N0 = A[0]; N1 = A[1]; }
        }

        float s = 0.0f;
        s += fmaxf(kMargin - (P0 - N0), 0.0f);
        s += fmaxf(kMargin - (P0 - N1), 0.0f);
        s += fmaxf(kMargin - (P1 - N0), 0.0f);
        s += fmaxf(kMargin - (P1 - N1), 0.0f);
        return 0.25f * s;
    };

    float acc = 0.0f;

    #pragma unroll 1
    for (int it = 0; it < kBodies; ++it) {
        const int u0   = wid * kUsersPerWave + it * kUsersPerBody;
        const int idxA = (u0 << 6) + (lane << 2);
        const int idxB = idxA + 256;
        const float4 vtA = *reinterpret_cast<const float4*>(y_true + idxA);
        const float4 vtB = *reinterpret_cast<const float4*>(y_true + idxB);
        const float4 vrA = *reinterpret_cast<const float4*>(rnd   + idxA);
        const float4 vrB = *reinterpret_cast<const float4*>(rnd   + idxB);
        const float4 vhA = *reinterpret_cast<const float4*>(y_hat + idxA);
        const float4 vhB = *reinterpret_cast<const float4*>(y_hat + idxB);
        // force all 6 loads to materialize here (R7: compiler sank B loads)
        asm volatile("" :: "v"(vtA.x), "v"(vtB.x), "v"(vrA.x),
                           "v"(vrB.x), "v"(vhA.x), "v"(vhB.x));

        acc += process(vhA, vtA, vrA);
        acc += process(vhB, vtB, vrB);
    }

    // acc is uniform within each 16-lane group; sum the 4 group leaders
    float contrib = (t == 0) ? acc : 0.0f;
    contrib += __shfl_xor(contrib, 32);
    contrib += __shfl_xor(contrib, 16);

    __shared__ float wsum[kWavesPerBlock];
    if (lane == 0) wsum[threadIdx.x >> 6] = contrib;
    __syncthreads();
    if (threadIdx.x == 0) {
        float tsum = 0.0f;
        #pragma unroll
        for (int i = 0; i < kWavesPerBlock; ++i) tsum += wsum[i];
        partials[blockIdx.x] = tsum;
    }
}

__global__ void prl_reduce_kernel(const float* __restrict__ partials,
                                  float* __restrict__ out)
{
    float tv = 0.0f;
    for (int i = threadIdx.x; i < kGrid; i += 256) tv += partials[i];
    #pragma unroll
    for (int s = 32; s > 0; s >>= 1) tv += __shfl_xor(tv, s);
    __shared__ float ws[4];
    if ((threadIdx.x & 63) == 0) ws[threadIdx.x >> 6] = tv;
    __syncthreads();
    if (threadIdx.x == 0) {
        out[0] = (ws[0] + ws[1] + ws[2] + ws[3]) * (1.0f / (float)kUsers);
    }
}

extern "C" void kernel_launch(void* const* d_in, const int* in_sizes, int n_in,
                              void* d_out, int out_size, void* d_ws, size_t ws_size,
                              hipStream_t stream) {
    const float* y_hat  = (const float*)d_in[0];
    const float* y_true = (const float*)d_in[1];
    const float* rnd    = (const float*)d_in[2];
    // d_in[3] = user_idx: contiguous equal-size segments -> never read
    float* partials = (float*)d_ws;          // kGrid floats = 8 KiB scratch
    float* out      = (float*)d_out;

    hipLaunchKernelGGL(prl_user_kernel, dim3(kGrid), dim3(kBlock), 0, stream,
                       y_hat, y_true, rnd, partials);
    hipLaunchKernelGGL(prl_reduce_kernel, dim3(1), dim3(256), 0, stream,
                       partials, out);
}

// Round 9
// 48.044 us; speedup vs baseline: 1.0211x; 1.0211x over previous
//
#include <hip/hip_runtime.h>

// PairwiseRankLoss: U=262144 users x G=64 items, K=2, MARGIN=0.3
// 4 users/wave group of 16 lanes, 4 items/lane (float4). R9:
//  - bitonic network remapped via GF(2)^3 linear map {1,2,4}->{1,2,7}:
//    physical lane p = M(logical tt); ALL sort exchanges are 1-instr DPP
//    (quad_perm xor1/xor2, half_mirror xor7). Zero ds_swizzle in sort.
//  - half B sorted descending (flipD absorbs half bit) -> median split =
//    min(w, ror8(w)); a31 = max-fold (3 DPP steps, period-8 data).
//  - selection keys embed the item index: key=(r&~63)|(63-idx); max-fold
//    yields winner index directly; gather via per-group LDS y_hat table
//    (uniform-address broadcast read). No ballot/locate.
//  - rotating 1-group register prefetch (no forced waits).
// Deterministic two-stage reduction via d_ws.

static constexpr int kUsers = 262144;
static constexpr int kBlock = 256;                  // 4 waves / block
static constexpr int kGrid  = 2048;
static constexpr int kWavesPerBlock = kBlock / 64;
static constexpr int kTotalWaves = kGrid * kWavesPerBlock;   // 8192
static constexpr int kUsersPerWave = kUsers / kTotalWaves;   // 32
static constexpr int kIters = kUsersPerWave / 4;             // 8
static constexpr float kMargin = 0.3f;

template<int CTRL>
static __device__ __forceinline__ float movdppf(float x) {
    return __uint_as_float((unsigned)__builtin_amdgcn_mov_dpp(
        (int)__float_as_uint(x), CTRL, 0xF, 0xF, false));
}
template<int CTRL>
static __device__ __forceinline__ unsigned movdppu(unsigned x) {
    return (unsigned)__builtin_amdgcn_mov_dpp((int)x, CTRL, 0xF, 0xF, false);
}
static __device__ __forceinline__ float xorf(float x, unsigned m) {
    return __uint_as_float(__float_as_uint(x) ^ m);
}
static __device__ __forceinline__ float cnd(float mx, float mn,
                                            unsigned long long keep) {
    float d;
    asm("v_cndmask_b32 %0, %1, %2, %3" : "=v"(d) : "v"(mx), "v"(mn), "s"(keep));
    return d;
}
// cross-lane CE in signed space: keep-min lanes per SGPR-pair mask
template<int CTRL>
static __device__ __forceinline__ float cexd(float w, unsigned long long keep) {
    const float p = movdppf<CTRL>(w);
    return cnd(fmaxf(w, p), fminf(w, p), keep);
}
static __device__ __forceinline__ unsigned umax_(unsigned a, unsigned b){ return a>b?a:b; }
static __device__ __forceinline__ unsigned umin_(unsigned a, unsigned b){ return a<b?a:b; }

#define CE2A(a, b) { float mn_=fminf(a,b), mx_=fmaxf(a,b); (a)=mn_; (b)=mx_; }
#define CE2D(a, b) { float mn_=fminf(a,b), mx_=fmaxf(a,b); (a)=mx_; (b)=mn_; }
#define FLIP4(m)   { w0=xorf(w0,m); w1=xorf(w1,m); w2=xorf(w2,m); w3=xorf(w3,m); }
#define CEX4(CTRL, keep) { w0=cexd<CTRL>(w0,keep); w1=cexd<CTRL>(w1,keep); \
                           w2=cexd<CTRL>(w2,keep); w3=cexd<CTRL>(w3,keep); }
#define FOLD2(m1, m2, CTRL) { \
    unsigned q1_ = movdppu<CTRL>(m1), q2_ = movdppu<CTRL>(m2); \
    unsigned lo_ = umin_(m1, q1_); \
    m1 = umax_(m1, q1_); \
    m2 = umax_(lo_, umax_(m2, q2_)); }

__global__ __launch_bounds__(kBlock, 8)
void prl_user_kernel(const float* __restrict__ y_hat,
                     const float* __restrict__ y_true,
                     const float* __restrict__ rnd,
                     float* __restrict__ partials)
{
    const int lane = threadIdx.x & 63;
    const int wid  = (blockIdx.x * kBlock + threadIdx.x) >> 6;
    const int t    = lane & 15;          // lane within user group
    const int g    = lane >> 4;          // user group (0..3) within wave

    // logical coords: p = physical 3-bit field, tt = M^-1(p)
    const int p2   = (t >> 2) & 1;
    const int tt0  = (t & 1) ^ p2;
    const int tt1  = ((t >> 1) & 1) ^ p2;
    const int tt2  = p2;
    const int half = (t >> 3) & 1;

    const unsigned SGN = 0x80000000u;
    const unsigned flipA = tt0 ? SGN : 0u;
    const unsigned flipB = (tt0 ^ tt1) ? SGN : 0u;
    const unsigned flipC = (tt1 ^ tt2) ? SGN : 0u;
    const unsigned flipD = (tt2 ^ half) ? SGN : 0u;   // + B-half descending
    const unsigned sgnB  = half ? SGN : 0u;
    const unsigned long long keep1 = __ballot(tt0 == 0);  // logical j=4
    const unsigned long long keep2 = __ballot(tt1 == 0);  // logical j=8
    const unsigned long long keep4 = __ballot(tt2 == 0);  // logical j=16

    // index-embedded key constants: inv = 63 - (4t + s)
    const unsigned cb = 63u - ((unsigned)t << 2);

    __shared__ float yh_tab[kWavesPerBlock][4][64];
    float* tab = &yh_tab[threadIdx.x >> 6][g][0];

    auto process = [&](float4 vh, float4 vt, float4 vr) -> float {
        // stage y_hat for winner gather (uniform-addr broadcast reads later)
        *reinterpret_cast<float4*>(tab + (t << 2)) = vh;

        // ---- signed-space bitonic, remapped lanes; halves A asc / B desc --
        float w0 = vt.x, w1 = vt.y, w2 = vt.z, w3 = vt.w;
        CE2A(w0, w1); CE2D(w2, w3);                    // k=2 (true space)
        FLIP4(flipA);
        CE2A(w0, w2); CE2A(w1, w3);                    // k=4 j=2
        CE2A(w0, w1); CE2A(w2, w3);                    //     j=1
        FLIP4(flipB);
        CEX4(0xB1, keep1);                             // k=8 j=4 (phys xor1)
        CE2A(w0, w2); CE2A(w1, w3);
        CE2A(w0, w1); CE2A(w2, w3);
        FLIP4(flipC);
        CEX4(0x4E, keep2);                             // k=16 j=8 (xor2)
        CEX4(0xB1, keep1);                             //      j=4
        CE2A(w0, w2); CE2A(w1, w3);
        CE2A(w0, w1); CE2A(w2, w3);
        FLIP4(flipD);
        CEX4(0x141, keep4);                            // k=32 j=16 (xor7)
        CEX4(0x4E, keep2);                             //      j=8
        CEX4(0xB1, keep1);                             //      j=4
        CE2A(w0, w2); CE2A(w1, w3);
        CE2A(w0, w1); CE2A(w2, w3);

        // unflip B half to true values; split = min with ror8 partner
        w0 = xorf(w0, sgnB); w1 = xorf(w1, sgnB);
        w2 = xorf(w2, sgnB); w3 = xorf(w3, sgnB);
        const float l0 = fminf(w0, movdppf<0x128>(w0));
        const float l1 = fminf(w1, movdppf<0x128>(w1));
        const float l2 = fminf(w2, movdppf<0x128>(w2));
        const float l3 = fminf(w3, movdppf<0x128>(w3));

        // a31 = max of lower-32 (data period-8 after split; 3 fold steps)
        float m = fmaxf(fmaxf(l0, l1), fmaxf(l2, l3));
        m = fmaxf(m, movdppf<0x124>(m));
        m = fmaxf(m, movdppf<0x122>(m));
        m = fmaxf(m, movdppf<0x121>(m));
        const float a31 = m;                           // group-uniform

        // ---- selection keys: (r & ~63) | (63 - item_idx) ----
        const bool p0m = vt.x > a31, p1m = vt.y > a31,
                   p2m = vt.z > a31, p3m = vt.w > a31;
        const unsigned kk0 = (__float_as_uint(vr.x) & ~63u) | cb;
        const unsigned kk1 = (__float_as_uint(vr.y) & ~63u) | (cb - 1u);
        const unsigned kk2 = (__float_as_uint(vr.z) & ~63u) | (cb - 2u);
        const unsigned kk3 = (__float_as_uint(vr.w) & ~63u) | (cb - 3u);

        auto top2 = [&](unsigned k0, unsigned k1, unsigned k2, unsigned k3,
                        unsigned& m1, unsigned& m2) {
            const unsigned a1 = umax_(k0,k1), a2 = umin_(k0,k1);
            const unsigned b1 = umax_(k2,k3), b2 = umin_(k2,k3);
            m1 = umax_(a1,b1);
            m2 = umax_(umin_(a1,b1), umax_(a2,b2));
            FOLD2(m1, m2, 0x128);
            FOLD2(m1, m2, 0x124);
            FOLD2(m1, m2, 0x122);
            FOLD2(m1, m2, 0x121);
        };
        unsigned pm1, pm2, nm1, nm2;
        top2(p0m ? kk0 : 0u, p1m ? kk1 : 0u, p2m ? kk2 : 0u, p3m ? kk3 : 0u,
             pm1, pm2);
        top2(p0m ? 0u : kk0, p1m ? 0u : kk1, p2m ? 0u : kk2, p3m ? 0u : kk3,
             nm1, nm2);

        // winner gather: idx = 63 - inv = (key&63)^63; uniform LDS reads
        const float P0 = tab[(pm1 & 63u) ^ 63u];
        const float P1 = tab[(pm2 & 63u) ^ 63u];
        const float N0 = tab[(nm1 & 63u) ^ 63u];
        const float N1 = tab[(nm2 & 63u) ^ 63u];

        float s = 0.0f;
        s += fmaxf(kMargin - (P0 - N0), 0.0f);
        s += fmaxf(kMargin - (P0 - N1), 0.0f);
        s += fmaxf(kMargin - (P1 - N0), 0.0f);
        s += fmaxf(kMargin - (P1 - N1), 0.0f);
        return 0.25f * s;
    };

    const int ub = wid * kUsersPerWave;
    #define LDIDX(i) (((ub + (i) * 4) << 6) + (lane << 2))
    float4 vt_c = *reinterpret_cast<const float4*>(y_true + LDIDX(0));
    float4 vr_c = *reinterpret_cast<const float4*>(rnd    + LDIDX(0));
    float4 vh_c = *reinterpret_cast<const float4*>(y_hat  + LDIDX(0));

    float acc = 0.0f;
    #pragma unroll 1
    for (int it = 0; it < kIters; ++it) {
        const int nx = (it + 1 < kIters) ? it + 1 : it;
        const float4 vt_n = *reinterpret_cast<const float4*>(y_true + LDIDX(nx));
        const float4 vr_n = *reinterpret_cast<const float4*>(rnd    + LDIDX(nx));
        const float4 vh_n = *reinterpret_cast<const float4*>(y_hat  + LDIDX(nx));
        acc += process(vh_c, vt_c, vr_c);
        vt_c = vt_n; vr_c = vr_n; vh_c = vh_n;
    }
    #undef LDIDX

    // acc uniform within each 16-lane group; sum the 4 group leaders
    float contrib = (t == 0) ? acc : 0.0f;
    contrib += __shfl_xor(contrib, 32);
    contrib += __shfl_xor(contrib, 16);

    __shared__ float wsum[kWavesPerBlock];
    if (lane == 0) wsum[threadIdx.x >> 6] = contrib;
    __syncthreads();
    if (threadIdx.x == 0) {
        float tsum = 0.0f;
        #pragma unroll
        for (int i = 0; i < kWavesPerBlock; ++i) tsum += wsum[i];
        partials[blockIdx.x] = tsum;
    }
}

__global__ void prl_reduce_kernel(const float* __restrict__ partials,
                                  float* __restrict__ out)
{
    float tv = 0.0f;
    for (int i = threadIdx.x; i < kGrid; i += 256) tv += partials[i];
    #pragma unroll
    for (int s = 32; s > 0; s >>= 1) tv += __shfl_xor(tv, s);
    __shared__ float ws[4];
    if ((threadIdx.x & 63) == 0) ws[threadIdx.x >> 6] = tv;
    __syncthreads();
    if (threadIdx.x == 0) {
        out[0] = (ws[0] + ws[1] + ws[2] + ws[3]) * (1.0f / (float)kUsers);
    }
}

extern "C" void kernel_launch(void* const* d_in, const int* in_sizes, int n_in,
                              void* d_out, int out_size, void* d_ws, size_t ws_size,
                              hipStream_t stream) {
    const float* y_hat  = (const float*)d_in[0];
    const float* y_true = (const float*)d_in[1];
    const float* rnd    = (const float*)d_in[2];
    // d_in[3] = user_idx: contiguous equal-size segments -> never read
    float* partials = (float*)d_ws;          // kGrid floats = 8 KiB scratch
    float* out      = (float*)d_out;

    hipLaunchKernelGGL(prl_user_kernel, dim3(kGrid), dim3(kBlock), 0, stream,
                       y_hat, y_true, rnd, partials);
    hipLaunchKernelGGL(prl_reduce_kernel, dim3(1), dim3(256), 0, stream,
                       partials, out);
}